// Round 3
// baseline (609.232 us; speedup 1.0000x reference)
//
#include <hip/hip_runtime.h>
#include <hip/hip_bf16.h>

typedef float f32x4 __attribute__((ext_vector_type(4)));
typedef __bf16 bf16x8 __attribute__((ext_vector_type(8)));
typedef unsigned short ushort_t;
typedef ushort_t u16x8 __attribute__((ext_vector_type(8)));

#define GLDS16(gp, lp)                                                        \
  __builtin_amdgcn_global_load_lds(                                           \
      (__attribute__((address_space(1))) void*)(gp),                          \
      (__attribute__((address_space(3))) void*)(lp), 16, 0, 0)

#define RAW_BARRIER() asm volatile("s_barrier" ::: "memory")
#define WAIT_VMCNT(n) asm volatile("s_waitcnt vmcnt(" #n ")" ::: "memory")

__device__ __forceinline__ ushort_t f2bf(float f) {
  unsigned u = __float_as_uint(f);
  unsigned r = u + 0x7fffu + ((u >> 16) & 1u);  // round-to-nearest-even
  return (ushort_t)(r >> 16);
}

__device__ __forceinline__ int swz(int row) {
  return (row & 3) ^ ((row >> 2) & 3);
}

// ---------------------------------------------------------------------------
// W1 [K=1024][N=1024] fp32 -> w1t [N][K] bf16 (transpose + convert)
// ---------------------------------------------------------------------------
__global__ __launch_bounds__(256) void prep_w1(const float* __restrict__ w1,
                                               ushort_t* __restrict__ w1t) {
  __shared__ ushort_t tile[64][80];
  const int k0 = blockIdx.x * 64;
  const int n0 = blockIdx.y * 64;
  const int tid = threadIdx.x;
#pragma unroll
  for (int it = 0; it < 16; ++it) {
    int idx = it * 256 + tid;
    int k = idx >> 6, n = idx & 63;
    tile[n][k] = f2bf(w1[(size_t)(k0 + k) * 1024 + n0 + n]);
  }
  __syncthreads();
#pragma unroll
  for (int it = 0; it < 2; ++it) {
    int idx = it * 256 + tid;
    int n = idx >> 3, kk = (idx & 7) * 8;
    bf16x8 v = *(const bf16x8*)&tile[n][kk];
    *(bf16x8*)&w1t[(size_t)(n0 + n) * 1024 + k0 + kk] = v;
  }
}

// ---------------------------------------------------------------------------
// x fp32 [64M] -> xbf bf16 row-major [65536][1024]
// ---------------------------------------------------------------------------
__global__ __launch_bounds__(256) void prep_x(const float* __restrict__ x,
                                              ushort_t* __restrict__ xbf) {
  size_t i = ((size_t)blockIdx.x * 256 + threadIdx.x) * 8;
  float4 a = *(const float4*)(x + i);
  float4 b = *(const float4*)(x + i + 4);
  u16x8 o;
  o[0] = f2bf(a.x); o[1] = f2bf(a.y); o[2] = f2bf(a.z); o[3] = f2bf(a.w);
  o[4] = f2bf(b.x); o[5] = f2bf(b.y); o[6] = f2bf(b.z); o[7] = f2bf(b.w);
  *(u16x8*)(xbf + i) = o;
}

// ---------------------------------------------------------------------------
// Fused kernel v3: BM=256 (two 128-row window strips), BN=256 per nt-pass,
// BK=32. 8 waves (512 thr), wave tile 128x64 (8x4 blocking of 16x16x32 ->
// 384 B LDS per MFMA). 3-buffer LDS ring with counted vmcnt: stage tile T+2
// during tile T (A in phase 0, B in phase 1), boundary s_waitcnt vmcnt(4)
// (tile T+1 drained, T+2's 4 loads stay in flight) -> never vmcnt(0) in the
// steady loop. Raw s_barrier (no compiler full-drain). 2 phases per tile:
// {stage || ds_read -> barrier -> setprio(1) 16 MFMA setprio(0) -> barrier}.
// ---------------------------------------------------------------------------
#define FOLD_EPILOGUE(ACC)                                                    \
  {                                                                           \
    float bv[4], wv[4];                                                       \
    _Pragma("unroll") for (int ni = 0; ni < 4; ++ni) {                        \
      int col = nt * 256 + wn + ni * 16 + lc;                                 \
      bv[ni] = b1[col];                                                       \
      wv[ni] = w2[col];                                                       \
    }                                                                         \
    _Pragma("unroll") for (int mi = 0; mi < 8; ++mi)                          \
        _Pragma("unroll") for (int r = 0; r < 4; ++r) {                       \
      float s = 0.f;                                                          \
      _Pragma("unroll") for (int ni = 0; ni < 4; ++ni) {                      \
        float h = ACC[mi][ni][r] + bv[ni];                                    \
        h = h > 0.f ? h : 0.f;                                                \
        s += h * wv[ni];                                                      \
      }                                                                       \
      racc[mi][r] += s;                                                       \
    }                                                                         \
  }

template <bool A_BF16>
__global__ __launch_bounds__(512, 2) void gemm_fused(
    const void* __restrict__ aglob, const ushort_t* __restrict__ w1t,
    const float* __restrict__ b1, const float* __restrict__ w2,
    const float* __restrict__ x, float* __restrict__ out) {
  __shared__ ushort_t As[3][256 * 32];  // 48 KB
  __shared__ ushort_t Bs[3][256 * 32];  // 48 KB
  __shared__ float lbuf[256];
  __shared__ float abuf[256];  // alpha[(s*32+j)*4 + k]

  const int tid = threadIdx.x;
  const int wave = tid >> 6, lane = tid & 63;
  const int quad = lane >> 4, lc = lane & 15;
  const int m0 = blockIdx.x * 256;
  const int wm = (wave & 1) * 128, wn = (wave >> 1) * 64;

  // Staging geometry: each tile half (A or B) is 256x32 bf16 = 16 KB =
  // 1024 x 16B chunks; thread covers chunks tid (rows 0-127) and 512+tid
  // (rows 128-255). Source column-chunk pre-swizzled (rule #21: inverse-swz
  // source + swz read; LDS dest linear as global_load_lds requires).
  const int rA = tid >> 2, cA = (tid & 3) ^ swz(tid >> 2);  // swz same for row+128

  const ushort_t* abf0 = nullptr; const ushort_t* abf1 = nullptr;
  const float* af0 = nullptr; const float* af1 = nullptr;
  if constexpr (A_BF16) {
    abf0 = (const ushort_t*)aglob + (size_t)(m0 + rA) * 1024 + cA * 8;
    abf1 = (const ushort_t*)aglob + (size_t)(m0 + 128 + rA) * 1024 + cA * 8;
  } else {
    af0 = (const float*)aglob + (size_t)(m0 + rA) * 1024 + cA * 8;
    af1 = (const float*)aglob + (size_t)(m0 + 128 + rA) * 1024 + cA * 8;
  }
  const ushort_t* bq0 = w1t + (size_t)rA * 1024 + cA * 8;
  const ushort_t* bq1 = w1t + (size_t)(128 + rA) * 1024 + cA * 8;

  int aoff[8], boff[4];
#pragma unroll
  for (int mi = 0; mi < 8; ++mi) {
    int r = wm + mi * 16 + lc;
    aoff[mi] = r * 32 + (quad ^ swz(r)) * 8;
  }
#pragma unroll
  for (int ni = 0; ni < 4; ++ni) {
    int r = wn + ni * 16 + lc;
    boff[ni] = r * 32 + (quad ^ swz(r)) * 8;
  }

  // Stage helpers for tile T (A half / B half). Pure async issue (bf16 path).
  auto stageA = [&](int buf, int T) {
    const int k0 = (T & 31) * 32;
    if constexpr (A_BF16) {
      GLDS16(abf0 + k0, &As[buf][tid * 8]);
      GLDS16(abf1 + k0, &As[buf][(512 + tid) * 8]);
    } else {
      float4 v0 = *(const float4*)(af0 + k0);
      float4 v1 = *(const float4*)(af0 + k0 + 4);
      float4 v2 = *(const float4*)(af1 + k0);
      float4 v3 = *(const float4*)(af1 + k0 + 4);
      u16x8 o0, o1;
      o0[0] = f2bf(v0.x); o0[1] = f2bf(v0.y); o0[2] = f2bf(v0.z); o0[3] = f2bf(v0.w);
      o0[4] = f2bf(v1.x); o0[5] = f2bf(v1.y); o0[6] = f2bf(v1.z); o0[7] = f2bf(v1.w);
      o1[0] = f2bf(v2.x); o1[1] = f2bf(v2.y); o1[2] = f2bf(v2.z); o1[3] = f2bf(v2.w);
      o1[4] = f2bf(v3.x); o1[5] = f2bf(v3.y); o1[6] = f2bf(v3.z); o1[7] = f2bf(v3.w);
      *(u16x8*)&As[buf][tid * 8] = o0;
      *(u16x8*)&As[buf][(512 + tid) * 8] = o1;
    }
  };
  auto stageB = [&](int buf, int T) {
    const int k0 = (T & 31) * 32;
    const size_t cb = (size_t)(T >> 5) * (256 * 1024);
    GLDS16(bq0 + cb + k0, &Bs[buf][tid * 8]);
    GLDS16(bq1 + cb + k0, &Bs[buf][(512 + tid) * 8]);
  };

  float racc[8][4] = {};
  f32x4 acc[8][4] = {};

  // Prologue: tiles 0 and 1 staged (bufs 0,1); drain tile 0 only (vmcnt(4)).
  stageA(0, 0); stageB(0, 0);
  stageA(1, 1); stageB(1, 1);
  if constexpr (A_BF16) { WAIT_VMCNT(4); } else { WAIT_VMCNT(2);
    asm volatile("s_waitcnt lgkmcnt(0)" ::: "memory"); }
  RAW_BARRIER();

  int cur = 0;
#pragma unroll 1
  for (int T = 0; T < 128; ++T) {
    const int nt = T >> 5;
    int stg = cur + 2; if (stg >= 3) stg -= 3;
    const bool doStage = (T + 2 < 128);

    // ---- phase 0: stage A(T+2) || read A-frags(mi 0-3) + all B-frags ----
    if (doStage) stageA(stg, T + 2);
    bf16x8 afr[4], bfr[4];
#pragma unroll
    for (int mi = 0; mi < 4; ++mi) afr[mi] = *(const bf16x8*)&As[cur][aoff[mi]];
#pragma unroll
    for (int ni = 0; ni < 4; ++ni) bfr[ni] = *(const bf16x8*)&Bs[cur][boff[ni]];
    RAW_BARRIER();
    __builtin_amdgcn_sched_barrier(0);
    __builtin_amdgcn_s_setprio(1);
#pragma unroll
    for (int mi = 0; mi < 4; ++mi)
#pragma unroll
      for (int ni = 0; ni < 4; ++ni)
        acc[mi][ni] = __builtin_amdgcn_mfma_f32_16x16x32_bf16(
            afr[mi], bfr[ni], acc[mi][ni], 0, 0, 0);
    __builtin_amdgcn_s_setprio(0);
    RAW_BARRIER();

    // ---- phase 1: stage B(T+2) || read A-frags(mi 4-7); reuse bfr ----
    if (doStage) stageB(stg, T + 2);
    bf16x8 afr2[4];
#pragma unroll
    for (int mi = 0; mi < 4; ++mi)
      afr2[mi] = *(const bf16x8*)&As[cur][aoff[4 + mi]];
    RAW_BARRIER();
    __builtin_amdgcn_sched_barrier(0);
    __builtin_amdgcn_s_setprio(1);
#pragma unroll
    for (int mi = 0; mi < 4; ++mi)
#pragma unroll
      for (int ni = 0; ni < 4; ++ni)
        acc[4 + mi][ni] = __builtin_amdgcn_mfma_f32_16x16x32_bf16(
            afr2[mi], bfr[ni], acc[4 + mi][ni], 0, 0, 0);
    __builtin_amdgcn_s_setprio(0);

    // ---- tile boundary: counted drain (tile T+1 ready; T+2 in flight) ----
    if constexpr (!A_BF16) asm volatile("s_waitcnt lgkmcnt(0)" ::: "memory");
    if (T <= 125) { WAIT_VMCNT(4); } else { WAIT_VMCNT(0); }
    RAW_BARRIER();
    cur = cur + 1; if (cur >= 3) cur = 0;

    if ((T & 31) == 31) {
      FOLD_EPILOGUE(acc)
#pragma unroll
      for (int mi = 0; mi < 8; ++mi)
#pragma unroll
        for (int ni = 0; ni < 4; ++ni) acc[mi][ni] = (f32x4){0.f, 0.f, 0.f, 0.f};
    }
  }

  // Reduce racc over the 16 lane-columns -> per-row logits in LDS.
#pragma unroll
  for (int mi = 0; mi < 8; ++mi)
#pragma unroll
    for (int r = 0; r < 4; ++r)
#pragma unroll
      for (int off = 1; off < 16; off <<= 1)
        racc[mi][r] += __shfl_xor(racc[mi][r], off, 64);
  __syncthreads();
  if (tid < 256) lbuf[tid] = 0.f;
  __syncthreads();
  if (lc == 0) {
#pragma unroll
    for (int mi = 0; mi < 8; ++mi)
#pragma unroll
      for (int r = 0; r < 4; ++r)
        atomicAdd(&lbuf[wm + mi * 16 + quad * 4 + r], racc[mi][r]);
  }
  __syncthreads();

  // Softmax per 2x2 window: 2 strips x 32 windows (b2 shift-invariant).
  if (tid < 64) {
    const int s = tid >> 5, j = tid & 31, base = s * 128;
    float l0 = lbuf[base + 2 * j], l1 = lbuf[base + 2 * j + 1];
    float l2 = lbuf[base + 64 + 2 * j], l3 = lbuf[base + 65 + 2 * j];
    float mx = fmaxf(fmaxf(l0, l1), fmaxf(l2, l3));
    float e0 = __expf(l0 - mx), e1 = __expf(l1 - mx);
    float e2 = __expf(l2 - mx), e3 = __expf(l3 - mx);
    float inv = 1.0f / (e0 + e1 + e2 + e3);
    abuf[tid * 4 + 0] = e0 * inv;
    abuf[tid * 4 + 1] = e1 * inv;
    abuf[tid * 4 + 2] = e2 * inv;
    abuf[tid * 4 + 3] = e3 * inv;
  }
  __syncthreads();

  // Weighted sum, both strips. 512 threads = 2 windows at once.
  const int jj = tid >> 8, t = tid & 255;
#pragma unroll 1
  for (int s = 0; s < 2; ++s) {
    const int g = blockIdx.x * 2 + s;
    const int b = g >> 5, ii = g & 31;
    const float* xs = x + (size_t)(m0 + s * 128) * 1024;
    float* orow = out + ((size_t)(b * 1024 + ii * 32)) * 1024;
    for (int j0 = 0; j0 < 32; j0 += 2) {
      int j = j0 + jj;
      float a0 = abuf[s * 128 + j * 4 + 0], a1 = abuf[s * 128 + j * 4 + 1];
      float a2 = abuf[s * 128 + j * 4 + 2], a3 = abuf[s * 128 + j * 4 + 3];
      const float4* p0 = (const float4*)(xs + (size_t)(2 * j) * 1024);
      const float4* p1 = (const float4*)(xs + (size_t)(2 * j + 1) * 1024);
      const float4* p2 = (const float4*)(xs + (size_t)(64 + 2 * j) * 1024);
      const float4* p3 = (const float4*)(xs + (size_t)(65 + 2 * j) * 1024);
      float4 v0 = p0[t], v1 = p1[t], v2 = p2[t], v3 = p3[t];
      float4 o;
      o.x = a0 * v0.x + a1 * v1.x + a2 * v2.x + a3 * v3.x;
      o.y = a0 * v0.y + a1 * v1.y + a2 * v2.y + a3 * v3.y;
      o.z = a0 * v0.z + a1 * v1.z + a2 * v2.z + a3 * v3.z;
      o.w = a0 * v0.w + a1 * v1.w + a2 * v2.w + a3 * v3.w;
      ((float4*)(orow + (size_t)j * 1024))[t] = o;
    }
  }
}

// ---------------------------------------------------------------------------
extern "C" void kernel_launch(void* const* d_in, const int* in_sizes, int n_in,
                              void* d_out, int out_size, void* d_ws,
                              size_t ws_size, hipStream_t stream) {
  const float* x  = (const float*)d_in[0];  // [16, 4096, 1024]
  const float* W1 = (const float*)d_in[1];  // [1024, 1024]
  const float* b1 = (const float*)d_in[2];  // [1024]
  const float* W2 = (const float*)d_in[3];  // [1024, 1]
  float* out = (float*)d_out;               // [16, 1024, 1024]

  const size_t XBF_BYTES = 134217728ull;  // 64M bf16
  const size_t W1T_BYTES = 2097152ull;

  if (ws_size >= XBF_BYTES + W1T_BYTES) {
    ushort_t* xbf = (ushort_t*)d_ws;
    ushort_t* w1t = (ushort_t*)((char*)d_ws + XBF_BYTES);
    prep_x<<<32768, 256, 0, stream>>>(x, xbf);
    prep_w1<<<dim3(16, 16), 256, 0, stream>>>(W1, w1t);
    gemm_fused<true><<<256, 512, 0, stream>>>(xbf, w1t, b1, W2, x, out);
  } else {
    ushort_t* w1t = (ushort_t*)d_ws;
    prep_w1<<<dim3(16, 16), 256, 0, stream>>>(W1, w1t);
    gemm_fused<false><<<256, 512, 0, stream>>>(x, w1t, b1, W2, x, out);
  }
}